// Round 1
// baseline (633.633 us; speedup 1.0000x reference)
//
#include <hip/hip_runtime.h>
#include <hip/hip_bf16.h>

// GCN forward: conv1(GEMM + sym-norm agg) -> BN -> PReLU -> conv2(GEMM + agg)
// N=100000, E=1600000, DIN=128, 2H=128, H=64. All fp32.
//
// Strategy:
//  - Build CSR (by dst) per launch: degree count -> 3-phase scan -> scatter.
//  - GEMMs: LDS-tiled fp32 (no fp32 MFMA on CDNA4), 64-row tiles, float4.
//  - Aggregation: one block per node, one thread per feature; coalesced row
//    gathers served mostly by Infinity Cache (h = 51MB < 256MB LLC).
//  - BN stats: 512-block reduction -> double atomics -> scale/shift folded
//    into GEMM2's LDS staging together with PReLU.

#define DIN 128
#define F1  128   // 2H
#define F2  64    // H
#define BN_EPS 1e-5f

// ---------------- graph build ----------------

__global__ __launch_bounds__(256) void count_deg_k(const int* __restrict__ dst,
                                                   int* __restrict__ degi, int e) {
    int i = blockIdx.x * 256 + threadIdx.x;
    if (i < e) atomicAdd(&degi[dst[i]], 1);
}

__global__ __launch_bounds__(256) void dinv_k(const int* __restrict__ degi,
                                              float* __restrict__ dinv, int n) {
    int i = blockIdx.x * 256 + threadIdx.x;
    if (i < n) dinv[i] = rsqrtf((float)(degi[i] + 1));  // +1 self-loop
}

// scan phase A: per-chunk (4096) sums
__global__ __launch_bounds__(256) void scan_a_k(const int* __restrict__ deg,
                                                int* __restrict__ part, int n) {
    __shared__ int red[256];
    int b = blockIdx.x, t = threadIdx.x;
    int base = b * 4096 + t * 16;
    int s = 0;
#pragma unroll
    for (int i = 0; i < 16; i++) {
        int idx = base + i;
        s += (idx < n) ? deg[idx] : 0;
    }
    red[t] = s;
    __syncthreads();
    for (int ofs = 128; ofs > 0; ofs >>= 1) {
        if (t < ofs) red[t] += red[t + ofs];
        __syncthreads();
    }
    if (t == 0) part[b] = red[0];
}

// scan phase B: serial exclusive scan of <=64 partials, write rowptr[n]=E
__global__ void scan_b_k(int* part, int* rowptr, int nb, int n) {
    if (threadIdx.x == 0 && blockIdx.x == 0) {
        int run = 0;
        for (int b = 0; b < nb; b++) { int x = part[b]; part[b] = run; run += x; }
        rowptr[n] = run;
    }
}

// scan phase C: per-chunk exclusive scan + global offset -> rowptr, rowcur
__global__ __launch_bounds__(256) void scan_c_k(const int* __restrict__ deg,
                                                const int* __restrict__ part,
                                                int* __restrict__ rowptr,
                                                int* __restrict__ rowcur, int n) {
    __shared__ int sums[256];
    int b = blockIdx.x, t = threadIdx.x;
    int base = b * 4096 + t * 16;
    int loc[16];
    int s = 0;
#pragma unroll
    for (int i = 0; i < 16; i++) {
        int idx = base + i;
        int d = (idx < n) ? deg[idx] : 0;
        loc[i] = s;  // thread-local exclusive
        s += d;
    }
    sums[t] = s;
    __syncthreads();
    int run = s;
    for (int ofs = 1; ofs < 256; ofs <<= 1) {
        int y = (t >= ofs) ? sums[t - ofs] : 0;
        __syncthreads();
        run += y;
        sums[t] = run;
        __syncthreads();
    }
    int offb = part[b] + (run - s);  // block offset + thread-exclusive
#pragma unroll
    for (int i = 0; i < 16; i++) {
        int idx = base + i;
        if (idx < n) {
            int v = offb + loc[i];
            rowptr[idx] = v;
            rowcur[idx] = v;
        }
    }
}

__global__ __launch_bounds__(256) void scatter_k(const int* __restrict__ src,
                                                 const int* __restrict__ dst,
                                                 int* __restrict__ rowcur,
                                                 int* __restrict__ srcsorted, int e) {
    int i = blockIdx.x * 256 + threadIdx.x;
    if (i < e) {
        int d = dst[i];
        int pos = atomicAdd(&rowcur[d], 1);
        srcsorted[pos] = src[i];
    }
}

// ---------------- GEMM1: h = x @ W1  (N x 128 @ 128 x 128) ----------------

__global__ __launch_bounds__(256) void gemm1_k(const float* __restrict__ x,
                                               const float* __restrict__ W,
                                               float* __restrict__ h, int n) {
    __shared__ float xs[64][DIN];
    int t = threadIdx.x;
    int row0 = blockIdx.x * 64;
    const float4* x4 = (const float4*)x;
#pragma unroll
    for (int i = 0; i < 8; i++) {
        int l = t + i * 256;       // float4 idx in 64x128 tile (2048 total)
        int r = l >> 5;            // 32 float4 per row
        int c = l & 31;
        float4 v = make_float4(0.f, 0.f, 0.f, 0.f);
        if (row0 + r < n) v = x4[(size_t)(row0 + r) * 32 + c];
        *(float4*)&xs[r][c * 4] = v;
    }
    __syncthreads();
    int cg = t & 31;       // 4-col group
    int r0 = (t >> 5) * 8; // 8 rows
    float acc[8][4];
#pragma unroll
    for (int r = 0; r < 8; r++)
#pragma unroll
        for (int c = 0; c < 4; c++) acc[r][c] = 0.f;
    const float4* W4 = (const float4*)W;
#pragma unroll 4
    for (int k = 0; k < DIN; k++) {
        float4 bv = W4[k * 32 + cg];
#pragma unroll
        for (int r = 0; r < 8; r++) {
            float a = xs[r0 + r][k];
            acc[r][0] = fmaf(a, bv.x, acc[r][0]);
            acc[r][1] = fmaf(a, bv.y, acc[r][1]);
            acc[r][2] = fmaf(a, bv.z, acc[r][2]);
            acc[r][3] = fmaf(a, bv.w, acc[r][3]);
        }
    }
    float4* h4 = (float4*)h;
#pragma unroll
    for (int r = 0; r < 8; r++) {
        int row = row0 + r0 + r;
        if (row < n)
            h4[(size_t)row * 32 + cg] = make_float4(acc[r][0], acc[r][1], acc[r][2], acc[r][3]);
    }
}

// ---------------- aggregation 1: z = D^-1/2 (A+I) D^-1/2 h + b1 ----------------

__global__ __launch_bounds__(128) void agg1_k(const float* __restrict__ h,
                                              const float* __restrict__ dinv,
                                              const int* __restrict__ rowptr,
                                              const int* __restrict__ srcs,
                                              const float* __restrict__ b1,
                                              float* __restrict__ z, int n) {
    int nd = blockIdx.x;
    int f = threadIdx.x;
    float di = dinv[nd];
    float acc = di * h[(size_t)nd * F1 + f];  // self-loop (x di at the end)
    int e = rowptr[nd], e1 = rowptr[nd + 1];
    for (; e + 4 <= e1; e += 4) {
        int s0 = srcs[e], s1 = srcs[e + 1], s2 = srcs[e + 2], s3 = srcs[e + 3];
        float d0 = dinv[s0], d1 = dinv[s1], d2 = dinv[s2], d3 = dinv[s3];
        float h0 = h[(size_t)s0 * F1 + f];
        float h1 = h[(size_t)s1 * F1 + f];
        float h2 = h[(size_t)s2 * F1 + f];
        float h3 = h[(size_t)s3 * F1 + f];
        acc = fmaf(d0, h0, acc);
        acc = fmaf(d1, h1, acc);
        acc = fmaf(d2, h2, acc);
        acc = fmaf(d3, h3, acc);
    }
    for (; e < e1; e++) {
        int s = srcs[e];
        acc = fmaf(dinv[s], h[(size_t)s * F1 + f], acc);
    }
    z[(size_t)nd * F1 + f] = fmaf(acc, di, b1[f]);
}

// ---------------- BatchNorm stats ----------------

__global__ __launch_bounds__(128) void bnstats_k(const float* __restrict__ z,
                                                 double* __restrict__ bnacc, int n) {
    int f = threadIdx.x;
    float s = 0.f, q = 0.f;
    for (int r = blockIdx.x; r < n; r += gridDim.x) {
        float v = z[(size_t)r * F1 + f];
        s += v;
        q = fmaf(v, v, q);
    }
    atomicAdd(&bnacc[f], (double)s);
    atomicAdd(&bnacc[F1 + f], (double)q);
}

__global__ __launch_bounds__(128) void bnfinal_k(const double* __restrict__ bnacc,
                                                 const float* __restrict__ gamma,
                                                 const float* __restrict__ beta,
                                                 float* __restrict__ scale,
                                                 float* __restrict__ shift, int n) {
    int f = threadIdx.x;
    double mean = bnacc[f] / n;
    double var = bnacc[F1 + f] / n - mean * mean;
    float sc = gamma[f] * rsqrtf((float)var + BN_EPS);
    scale[f] = sc;
    shift[f] = beta[f] - (float)mean * sc;
}

// ---------- GEMM2: h2 = prelu(bn(z)) @ W2  (N x 128 @ 128 x 64) ----------

__global__ __launch_bounds__(256) void gemm2_k(const float* __restrict__ z,
                                               const float* __restrict__ W,
                                               const float* __restrict__ scale,
                                               const float* __restrict__ shift,
                                               const float* __restrict__ prelu_a,
                                               float* __restrict__ h2, int n) {
    __shared__ float zs[64][F1];
    int t = threadIdx.x;
    int row0 = blockIdx.x * 64;
    float pa = prelu_a[0];
    const float4* z4 = (const float4*)z;
    const float4* sc4 = (const float4*)scale;
    const float4* sh4 = (const float4*)shift;
#pragma unroll
    for (int i = 0; i < 8; i++) {
        int l = t + i * 256;
        int r = l >> 5;
        int c = l & 31;
        float4 v = make_float4(0.f, 0.f, 0.f, 0.f);
        if (row0 + r < n) v = z4[(size_t)(row0 + r) * 32 + c];
        float4 sc = sc4[c], sh = sh4[c];
        v.x = fmaf(v.x, sc.x, sh.x); v.x = v.x >= 0.f ? v.x : pa * v.x;
        v.y = fmaf(v.y, sc.y, sh.y); v.y = v.y >= 0.f ? v.y : pa * v.y;
        v.z = fmaf(v.z, sc.z, sh.z); v.z = v.z >= 0.f ? v.z : pa * v.z;
        v.w = fmaf(v.w, sc.w, sh.w); v.w = v.w >= 0.f ? v.w : pa * v.w;
        *(float4*)&zs[r][c * 4] = v;
    }
    __syncthreads();
    int cg = t & 15;        // 4-col group (64 cols -> 16 groups)
    int r0 = (t >> 4) * 4;  // 4 rows
    float acc[4][4];
#pragma unroll
    for (int r = 0; r < 4; r++)
#pragma unroll
        for (int c = 0; c < 4; c++) acc[r][c] = 0.f;
    const float4* W4 = (const float4*)W;
#pragma unroll 4
    for (int k = 0; k < F1; k++) {
        float4 bv = W4[k * 16 + cg];
#pragma unroll
        for (int r = 0; r < 4; r++) {
            float a = zs[r0 + r][k];
            acc[r][0] = fmaf(a, bv.x, acc[r][0]);
            acc[r][1] = fmaf(a, bv.y, acc[r][1]);
            acc[r][2] = fmaf(a, bv.z, acc[r][2]);
            acc[r][3] = fmaf(a, bv.w, acc[r][3]);
        }
    }
    float4* o4 = (float4*)h2;
#pragma unroll
    for (int r = 0; r < 4; r++) {
        int row = row0 + r0 + r;
        if (row < n)
            o4[(size_t)row * 16 + cg] = make_float4(acc[r][0], acc[r][1], acc[r][2], acc[r][3]);
    }
}

// ---------------- aggregation 2 -> output ----------------

__global__ __launch_bounds__(64) void agg2_k(const float* __restrict__ h,
                                             const float* __restrict__ dinv,
                                             const int* __restrict__ rowptr,
                                             const int* __restrict__ srcs,
                                             const float* __restrict__ b2,
                                             float* __restrict__ out, int n) {
    int nd = blockIdx.x;
    int f = threadIdx.x;
    float di = dinv[nd];
    float acc = di * h[(size_t)nd * F2 + f];
    int e = rowptr[nd], e1 = rowptr[nd + 1];
    for (; e + 4 <= e1; e += 4) {
        int s0 = srcs[e], s1 = srcs[e + 1], s2 = srcs[e + 2], s3 = srcs[e + 3];
        float d0 = dinv[s0], d1 = dinv[s1], d2 = dinv[s2], d3 = dinv[s3];
        float h0 = h[(size_t)s0 * F2 + f];
        float h1 = h[(size_t)s1 * F2 + f];
        float h2 = h[(size_t)s2 * F2 + f];
        float h3 = h[(size_t)s3 * F2 + f];
        acc = fmaf(d0, h0, acc);
        acc = fmaf(d1, h1, acc);
        acc = fmaf(d2, h2, acc);
        acc = fmaf(d3, h3, acc);
    }
    for (; e < e1; e++) {
        int s = srcs[e];
        acc = fmaf(dinv[s], h[(size_t)s * F2 + f], acc);
    }
    out[(size_t)nd * F2 + f] = fmaf(acc, di, b2[f]);
}

// ---------------- launch ----------------

extern "C" void kernel_launch(void* const* d_in, const int* in_sizes, int n_in,
                              void* d_out, int out_size, void* d_ws, size_t ws_size,
                              hipStream_t stream) {
    const float* x       = (const float*)d_in[0];
    const int*   ei      = (const int*)d_in[1];
    const float* W1      = (const float*)d_in[2];
    const float* b1      = (const float*)d_in[3];
    const float* W2      = (const float*)d_in[4];
    const float* b2      = (const float*)d_in[5];
    const float* gamma   = (const float*)d_in[6];
    const float* beta    = (const float*)d_in[7];
    const float* prelu_a = (const float*)d_in[8];

    const int N = in_sizes[0] / DIN;
    const int E = in_sizes[1] / 2;
    const int* src = ei;
    const int* dst = ei + E;

    char* p = (char*)d_ws;
    size_t off = 0;
    auto take = [&](size_t bytes) -> char* {
        char* r = p + off;
        off = (off + bytes + 255) & ~(size_t)255;
        return r;
    };
    int*    degi      = (int*)take((size_t)N * 4);
    float*  dinv      = (float*)take((size_t)N * 4);
    int*    rowptr    = (int*)take((size_t)(N + 1) * 4);
    int*    rowcur    = (int*)take((size_t)N * 4);
    int*    partials  = (int*)take(64 * 4);
    int*    srcsorted = (int*)take((size_t)E * 4);
    double* bnacc     = (double*)take(2 * F1 * 8);
    float*  scale     = (float*)take(F1 * 4);
    float*  shift     = (float*)take(F1 * 4);
    float*  h         = (float*)take((size_t)N * F1 * 4);
    float*  z         = (float*)take((size_t)N * F1 * 4);
    float*  h2        = h;  // h dead after agg1; reuse for conv2 pre-agg
    float*  out       = (float*)d_out;

    hipMemsetAsync(degi, 0, (size_t)N * 4, stream);
    hipMemsetAsync(bnacc, 0, 2 * F1 * 8, stream);

    const int eb = (E + 255) / 256;
    const int NB = (N + 4095) / 4096;

    count_deg_k<<<eb, 256, 0, stream>>>(dst, degi, E);
    dinv_k<<<(N + 255) / 256, 256, 0, stream>>>(degi, dinv, N);
    scan_a_k<<<NB, 256, 0, stream>>>(degi, partials, N);
    scan_b_k<<<1, 64, 0, stream>>>(partials, rowptr, NB, N);
    scan_c_k<<<NB, 256, 0, stream>>>(degi, partials, rowptr, rowcur, N);
    scatter_k<<<eb, 256, 0, stream>>>(src, dst, rowcur, srcsorted, E);

    gemm1_k<<<(N + 63) / 64, 256, 0, stream>>>(x, W1, h, N);
    agg1_k<<<N, F1, 0, stream>>>(h, dinv, rowptr, srcsorted, b1, z, N);
    bnstats_k<<<512, F1, 0, stream>>>(z, bnacc, N);
    bnfinal_k<<<1, F1, 0, stream>>>(bnacc, gamma, beta, scale, shift, N);
    gemm2_k<<<(N + 63) / 64, 256, 0, stream>>>(z, W2, scale, shift, prelu_a, h2, N);
    agg2_k<<<N, F2, 0, stream>>>(h2, dinv, rowptr, srcsorted, b2, out, N);
}